// Round 4
// baseline (478.982 us; speedup 1.0000x reference)
//
#include <hip/hip_runtime.h>

#define WID 256
#define EPS_GN 1e-5f

typedef __bf16 v8bf __attribute__((ext_vector_type(8)));
typedef float  v4f  __attribute__((ext_vector_type(4)));

__device__ inline unsigned short f2b(float f) {
    unsigned int u = __builtin_bit_cast(unsigned int, f);
    unsigned int r = (u + 0x7fffu + ((u >> 16) & 1u)) >> 16;
    return (unsigned short)r;
}
__device__ inline __bf16 f2bf(float f) {
    unsigned short s = f2b(f);
    return __builtin_bit_cast(__bf16, s);
}

// ---------- cast all weights to bf16 ----------
__global__ void cast_k(const float* __restrict__ Wsrc, const float* __restrict__ Wtgt,
                       const float* __restrict__ Wp, const float* __restrict__ Wg,
                       const float* __restrict__ Wv, unsigned short* __restrict__ Wsb,
                       unsigned short* __restrict__ Wtb, unsigned short* __restrict__ Wpb,
                       unsigned short* __restrict__ Wgb, unsigned short* __restrict__ Wvb) {
    int i = blockIdx.x * 256 + threadIdx.x;
    if (i < 65536) { Wsb[i] = f2b(Wsrc[i]); Wtb[i] = f2b(Wtgt[i]); Wpb[i] = f2b(Wp[i]); }
    if (i < 8192)  { Wgb[i] = f2b(Wg[i]);  Wvb[i] = f2b(Wv[i]); }
}

// ---------- counting sort by target: histogram ----------
__global__ void hist_k(const int* __restrict__ eidx, int* __restrict__ cnt, int E) {
    int i = blockIdx.x * 256 + threadIdx.x;
    if (i < E) atomicAdd(&cnt[eidx[E + i]], 1);
}

// ---------- exclusive scan of cnt -> cur (single block) ----------
__global__ void scan_k(const int* __restrict__ cnt, int* __restrict__ cur, int N) {
    __shared__ int part[256];
    int t = threadIdx.x;
    int C = (N + 255) / 256;
    int s = 0;
    for (int i = 0; i < C; i++) { int idx = t * C + i; if (idx < N) s += cnt[idx]; }
    part[t] = s;
    __syncthreads();
    for (int d = 1; d < 256; d <<= 1) {
        int v = (t >= d) ? part[t - d] : 0;
        __syncthreads();
        part[t] += v;
        __syncthreads();
    }
    int base = (t == 0) ? 0 : part[t - 1];
    for (int i = 0; i < C; i++) {
        int idx = t * C + i;
        if (idx < N) { cur[idx] = base; base += cnt[idx]; }
    }
}

// ---------- scatter edge ids into sorted order ----------
__global__ void scat_k(const int* __restrict__ eidx, int* __restrict__ cur,
                       int* __restrict__ perm, int E) {
    int i = blockIdx.x * 256 + threadIdx.x;
    if (i < E) { int p = atomicAdd(&cur[eidx[E + i]], 1); perm[p] = i; }
}

// ---------- node projections via MFMA: xs = x@Wsrc^T, xt = x@Wtgt^T ----------
__global__ __launch_bounds__(256, 2)
void proj_k(const float* __restrict__ x, const unsigned short* __restrict__ Wsb,
            const unsigned short* __restrict__ Wtb, float* __restrict__ xs,
            float* __restrict__ xt, int N) {
    __shared__ unsigned short ab[64 * 264];
    int t = threadIdx.x;
    int n0 = blockIdx.x * 64;
#pragma unroll
    for (int ch = 0; ch < 16; ch++) {
        int flat = ch * 1024 + t * 4;
        int row = flat >> 8, col = flat & 255;
        int n = n0 + row;
        float4 v = (n < N) ? *(const float4*)&x[(size_t)n * WID + col]
                           : make_float4(0.f, 0.f, 0.f, 0.f);
        unsigned int p0 = (unsigned int)f2b(v.x) | ((unsigned int)f2b(v.y) << 16);
        unsigned int p1 = (unsigned int)f2b(v.z) | ((unsigned int)f2b(v.w) << 16);
        *(uint2*)&ab[row * 264 + col] = make_uint2(p0, p1);
    }
    __syncthreads();
    int w = t >> 6, lane = t & 63, m = lane & 15, kg = lane >> 4;
#pragma unroll
    for (int pass = 0; pass < 2; pass++) {
        const unsigned short* Wb = pass ? Wtb : Wsb;
        float* outp = pass ? xt : xs;
        v4f acc[4][4];
#pragma unroll
        for (int mt = 0; mt < 4; mt++)
#pragma unroll
            for (int nt = 0; nt < 4; nt++) acc[mt][nt] = (v4f){0.f, 0.f, 0.f, 0.f};
#pragma unroll
        for (int kt = 0; kt < 8; kt++) {
            int k0 = kt * 32 + kg * 8;
            v8bf a[4];
#pragma unroll
            for (int mt = 0; mt < 4; mt++)
                a[mt] = *(const v8bf*)&ab[(mt * 16 + m) * 264 + k0];
#pragma unroll
            for (int nt = 0; nt < 4; nt++) {
                int j = w * 64 + nt * 16 + m;
                v8bf b = *(const v8bf*)&Wb[j * 256 + k0];
#pragma unroll
                for (int mt = 0; mt < 4; mt++)
                    acc[mt][nt] = __builtin_amdgcn_mfma_f32_16x16x32_bf16(a[mt], b, acc[mt][nt], 0, 0, 0);
            }
        }
#pragma unroll
        for (int mt = 0; mt < 4; mt++)
#pragma unroll
            for (int r = 0; r < 4; r++) {
                int n = n0 + mt * 16 + kg * 4 + r;
                if (n < N)
#pragma unroll
                    for (int nt = 0; nt < 4; nt++)
                        outp[(size_t)n * WID + w * 64 + nt * 16 + m] = acc[mt][nt][r];
            }
        __syncthreads();
    }
}

// ---------- fused edge pipeline on target-sorted edges ----------
__global__ __launch_bounds__(256, 3)
void edge_k(const float* __restrict__ xs, const float* __restrict__ xt,
            const int* __restrict__ eidx, const int* __restrict__ eattr,
            const int* __restrict__ perm, const float* __restrict__ emb,
            const unsigned short* __restrict__ Wgb, const unsigned short* __restrict__ Wvb,
            float* __restrict__ aggact, int E) {
    __shared__ float xx[32 * 260];             // fp32; reused as act buffer after P5 frag loads
    __shared__ unsigned short ginb[32 * 264];  // bf16 xn + bag bias
    __shared__ float mu_s[256], rs_s[256];
    __shared__ int perm_s[32], src_s[32], tgt_s[32], attr_s[96];

    int t = threadIdx.x;
    int e0 = blockIdx.x * 32;
    int ne = min(32, E - e0);

    if (t < 32) {
        int p = (t < ne) ? perm[e0 + t] : -1;
        perm_s[t] = p;
        src_s[t] = (p >= 0) ? eidx[p] : 0;
        tgt_s[t] = (p >= 0) ? eidx[E + p] : 0;
    }
    __syncthreads();
    if (t < 96) {
        int e = t / 3, c = t - e * 3;
        int p = perm_s[e];
        attr_s[t] = (p >= 0) ? eattr[(size_t)p * 3 + c] : 0;
    }

    // P1: vectorized gather xs[src]+xt[tgt] -> xx.  thread -> (edge e=t>>3, chunk c=t&7)
    {
        int e = t >> 3, c = t & 7;
        int s = src_s[e], g = tgt_s[e];
        const float4* ps = (const float4*)&xs[(size_t)s * WID];
        const float4* pt = (const float4*)&xt[(size_t)g * WID];
        bool live = (e < ne);
#pragma unroll
        for (int i = 0; i < 8; i++) {
            int c4 = c + i * 8;
            float4 a = ps[c4], b = pt[c4];
            float4 v;
            v.x = live ? a.x + b.x : 0.f; v.y = live ? a.y + b.y : 0.f;
            v.z = live ? a.z + b.z : 0.f; v.w = live ? a.w + b.w : 0.f;
            *(float4*)&xx[e * 260 + c4 * 4] = v;
        }
    }
    __syncthreads();

    // P2: group stats, one (e,h) per thread, rotated reads
    {
        int e = t >> 3, h = t & 7;
        int base = e * 260 + h * 32;
        float sum = 0.f, sq = 0.f;
#pragma unroll
        for (int i = 0; i < 32; i++) {
            int d = (t + i) & 31;
            float v = xx[base + d];
            sum += v; sq += v * v;
        }
        float mu = sum * (1.f / 32.f);
        float var = sq * (1.f / 32.f) - mu * mu;
        mu_s[t] = mu;
        rs_s[t] = rsqrtf(var + EPS_GN);
    }
    __syncthreads();

    // P4: normalize xx in place (fp32) + write bf16 gate input (xn + bag bias). column t.
    {
        int h = t >> 5;
        for (int e = 0; e < 32; e++) {
            int si = e * 8 + h;
            float xn = (xx[e * 260 + t] - mu_s[si]) * rs_s[si];
            xx[e * 260 + t] = xn;
            float b = 0.f; int cnt = 0;
#pragma unroll
            for (int c = 0; c < 3; c++) {
                int idx = attr_s[e * 3 + c];
                if (idx != 0) { b += emb[idx * WID + t]; cnt++; }
            }
            b *= (cnt > 0) ? (1.f / (float)cnt) : 1.f;
            ginb[e * 264 + t] = f2b(xn + b);
        }
    }
    __syncthreads();

    // P5: load frags -> barrier -> gate/val MFMA -> store act into xx (reuse)
    {
        int w = t >> 6, lane = t & 63;
        int m = lane & 15, kg = lane >> 4;
        v8bf av[2][2], ag[2][2], bg[2][2], bv[2][2];
#pragma unroll
        for (int hh = 0; hh < 2; hh++) {
            int h = w * 2 + hh;
            const float* p0 = &xx[m * 260 + h * 32 + kg * 8];
            const float* p1 = &xx[(16 + m) * 260 + h * 32 + kg * 8];
            float4 x0 = *(const float4*)p0, x1 = *(const float4*)(p0 + 4);
            float4 y0 = *(const float4*)p1, y1 = *(const float4*)(p1 + 4);
            av[hh][0][0]=f2bf(x0.x); av[hh][0][1]=f2bf(x0.y); av[hh][0][2]=f2bf(x0.z); av[hh][0][3]=f2bf(x0.w);
            av[hh][0][4]=f2bf(x1.x); av[hh][0][5]=f2bf(x1.y); av[hh][0][6]=f2bf(x1.z); av[hh][0][7]=f2bf(x1.w);
            av[hh][1][0]=f2bf(y0.x); av[hh][1][1]=f2bf(y0.y); av[hh][1][2]=f2bf(y0.z); av[hh][1][3]=f2bf(y0.w);
            av[hh][1][4]=f2bf(y1.x); av[hh][1][5]=f2bf(y1.y); av[hh][1][6]=f2bf(y1.z); av[hh][1][7]=f2bf(y1.w);
            ag[hh][0] = *(const v8bf*)&ginb[m * 264 + h * 32 + kg * 8];
            ag[hh][1] = *(const v8bf*)&ginb[(16 + m) * 264 + h * 32 + kg * 8];
            bg[hh][0] = *(const v8bf*)&Wgb[h * 1024 + m * 32 + kg * 8];
            bg[hh][1] = *(const v8bf*)&Wgb[h * 1024 + (16 + m) * 32 + kg * 8];
            bv[hh][0] = *(const v8bf*)&Wvb[h * 1024 + m * 32 + kg * 8];
            bv[hh][1] = *(const v8bf*)&Wvb[h * 1024 + (16 + m) * 32 + kg * 8];
        }
        __syncthreads();  // all frag reads of xx done before act overwrites it
#pragma unroll
        for (int hh = 0; hh < 2; hh++) {
            int h = w * 2 + hh;
            v4f z = {0.f, 0.f, 0.f, 0.f};
            v4f g00 = __builtin_amdgcn_mfma_f32_16x16x32_bf16(ag[hh][0], bg[hh][0], z, 0, 0, 0);
            v4f g01 = __builtin_amdgcn_mfma_f32_16x16x32_bf16(ag[hh][0], bg[hh][1], z, 0, 0, 0);
            v4f g10 = __builtin_amdgcn_mfma_f32_16x16x32_bf16(ag[hh][1], bg[hh][0], z, 0, 0, 0);
            v4f g11 = __builtin_amdgcn_mfma_f32_16x16x32_bf16(ag[hh][1], bg[hh][1], z, 0, 0, 0);
            v4f v00 = __builtin_amdgcn_mfma_f32_16x16x32_bf16(av[hh][0], bv[hh][0], z, 0, 0, 0);
            v4f v01 = __builtin_amdgcn_mfma_f32_16x16x32_bf16(av[hh][0], bv[hh][1], z, 0, 0, 0);
            v4f v10 = __builtin_amdgcn_mfma_f32_16x16x32_bf16(av[hh][1], bv[hh][0], z, 0, 0, 0);
            v4f v11 = __builtin_amdgcn_mfma_f32_16x16x32_bf16(av[hh][1], bv[hh][1], z, 0, 0, 0);
            // C layout: row e = tile*16 + kg*4 + r, col = h*32 + (ntile*16 + m)
#pragma unroll
            for (int r = 0; r < 4; r++) {
                int eA = kg * 4 + r, eB = eA + 16;
                xx[eA * 260 + h * 32 + m]      = fmaxf(g00[r], 0.f) * v00[r];
                xx[eA * 260 + h * 32 + 16 + m] = fmaxf(g01[r], 0.f) * v01[r];
                xx[eB * 260 + h * 32 + m]      = fmaxf(g10[r], 0.f) * v10[r];
                xx[eB * 260 + h * 32 + 16 + m] = fmaxf(g11[r], 0.f) * v11[r];
            }
        }
    }
    __syncthreads();

    // P6: segmented column reduce over sorted targets -> few atomics
    {
        float sum = 0.f;
        int prev = tgt_s[0];
        for (int e = 0; e < ne; e++) {
            int tg = tgt_s[e];
            if (tg != prev) {
                atomicAdd(&aggact[(size_t)prev * WID + t], sum);
                sum = 0.f;
                prev = tg;
            }
            sum += xx[e * 260 + t];
        }
        atomicAdd(&aggact[(size_t)prev * WID + t], sum);
    }
}

// ---------- post: out = deg^p ⊙ (aggact @ Wp^T), MFMA + fused rescale ----------
__global__ __launch_bounds__(256, 2)
void post_k(const float* __restrict__ aggact, const unsigned short* __restrict__ Wpb,
            const float* __restrict__ deg, const float* __restrict__ dp,
            float* __restrict__ out, int N) {
    __shared__ unsigned short ab[64 * 264];
    __shared__ float degl[64];
    int t = threadIdx.x;
    int n0 = blockIdx.x * 64;
#pragma unroll
    for (int ch = 0; ch < 16; ch++) {
        int flat = ch * 1024 + t * 4;
        int row = flat >> 8, col = flat & 255;
        int n = n0 + row;
        float4 v = (n < N) ? *(const float4*)&aggact[(size_t)n * WID + col]
                           : make_float4(0.f, 0.f, 0.f, 0.f);
        unsigned int p0 = (unsigned int)f2b(v.x) | ((unsigned int)f2b(v.y) << 16);
        unsigned int p1 = (unsigned int)f2b(v.z) | ((unsigned int)f2b(v.w) << 16);
        *(uint2*)&ab[row * 264 + col] = make_uint2(p0, p1);
    }
    if (t < 64) {
        int n = n0 + t;
        degl[t] = (n < N) ? log2f(deg[n]) : 0.f;
    }
    __syncthreads();
    int w = t >> 6, lane = t & 63, m = lane & 15, kg = lane >> 4;
    v4f acc[4][4];
#pragma unroll
    for (int mt = 0; mt < 4; mt++)
#pragma unroll
        for (int nt = 0; nt < 4; nt++) acc[mt][nt] = (v4f){0.f, 0.f, 0.f, 0.f};
#pragma unroll
    for (int kt = 0; kt < 8; kt++) {
        int k0 = kt * 32 + kg * 8;
        v8bf a[4];
#pragma unroll
        for (int mt = 0; mt < 4; mt++)
            a[mt] = *(const v8bf*)&ab[(mt * 16 + m) * 264 + k0];
#pragma unroll
        for (int nt = 0; nt < 4; nt++) {
            int j = w * 64 + nt * 16 + m;
            v8bf b = *(const v8bf*)&Wpb[j * 256 + k0];
#pragma unroll
            for (int mt = 0; mt < 4; mt++)
                acc[mt][nt] = __builtin_amdgcn_mfma_f32_16x16x32_bf16(a[mt], b, acc[mt][nt], 0, 0, 0);
        }
    }
    float dpv[4];
#pragma unroll
    for (int nt = 0; nt < 4; nt++) dpv[nt] = dp[w * 64 + nt * 16 + m];
#pragma unroll
    for (int mt = 0; mt < 4; mt++)
#pragma unroll
        for (int r = 0; r < 4; r++) {
            int row = mt * 16 + kg * 4 + r;
            int n = n0 + row;
            if (n < N) {
                float ld = degl[row];
#pragma unroll
                for (int nt = 0; nt < 4; nt++)
                    out[(size_t)n * WID + w * 64 + nt * 16 + m] =
                        exp2f(dpv[nt] * ld) * acc[mt][nt][r];
            }
        }
}

extern "C" void kernel_launch(void* const* d_in, const int* in_sizes, int n_in,
                              void* d_out, int out_size, void* d_ws, size_t ws_size,
                              hipStream_t stream) {
    const float* x    = (const float*)d_in[0];
    const float* deg  = (const float*)d_in[1];
    const int*   eidx = (const int*)d_in[2];
    const int*   eatt = (const int*)d_in[3];
    const float* Wsrc = (const float*)d_in[4];
    const float* Wtgt = (const float*)d_in[5];
    const float* emb  = (const float*)d_in[6];
    const float* Wg   = (const float*)d_in[7];
    const float* Wv   = (const float*)d_in[8];
    const float* Wp   = (const float*)d_in[9];
    const float* dp   = (const float*)d_in[10];
    int N = in_sizes[0] / WID;
    int E = in_sizes[2] / 2;

    float* ws     = (float*)d_ws;
    float* xs     = ws;                         // N*W
    float* xt     = xs + (size_t)N * WID;       // N*W
    float* aggact = xt + (size_t)N * WID;       // N*W
    int*   cnt    = (int*)(aggact + (size_t)N * WID);  // N (zeroed with aggact)
    int*   cur    = cnt + N;                    // N
    int*   perm   = cur + N;                    // E
    unsigned short* Wsb = (unsigned short*)(perm + E);
    unsigned short* Wtb = Wsb + 65536;
    unsigned short* Wpb = Wtb + 65536;
    unsigned short* Wgb = Wpb + 65536;
    unsigned short* Wvb = Wgb + 8192;

    // zero aggact + cnt in one memset (contiguous)
    hipMemsetAsync(aggact, 0, ((size_t)N * WID + N) * sizeof(float), stream);
    cast_k<<<256, 256, 0, stream>>>(Wsrc, Wtgt, Wp, Wg, Wv, Wsb, Wtb, Wpb, Wgb, Wvb);
    hist_k<<<(E + 255) / 256, 256, 0, stream>>>(eidx, cnt, E);
    scan_k<<<1, 256, 0, stream>>>(cnt, cur, N);
    scat_k<<<(E + 255) / 256, 256, 0, stream>>>(eidx, cur, perm, E);
    proj_k<<<(N + 63) / 64, 256, 0, stream>>>(x, Wsb, Wtb, xs, xt, N);
    edge_k<<<(E + 31) / 32, 256, 0, stream>>>(xs, xt, eidx, eatt, perm, emb, Wgb, Wvb, aggact, E);
    post_k<<<(N + 63) / 64, 256, 0, stream>>>(aggact, Wpb, deg, dp, (float*)d_out, N);
}

// Round 5
// 426.929 us; speedup vs baseline: 1.1219x; 1.1219x over previous
//
#include <hip/hip_runtime.h>

#define WID 256
#define EPS_GN 1e-5f

typedef __bf16 v8bf __attribute__((ext_vector_type(8)));
typedef float  v4f  __attribute__((ext_vector_type(4)));

__device__ inline unsigned short f2b(float f) {
    unsigned int u = __builtin_bit_cast(unsigned int, f);
    unsigned int r = (u + 0x7fffu + ((u >> 16) & 1u)) >> 16;
    return (unsigned short)r;
}
__device__ inline float b2f(unsigned short s) {
    unsigned int u = (unsigned int)s << 16;
    return __builtin_bit_cast(float, u);
}

// ---------- cast all weights to bf16 ----------
__global__ void cast_k(const float* __restrict__ Wsrc, const float* __restrict__ Wtgt,
                       const float* __restrict__ Wp, const float* __restrict__ Wg,
                       const float* __restrict__ Wv, unsigned short* __restrict__ Wsb,
                       unsigned short* __restrict__ Wtb, unsigned short* __restrict__ Wpb,
                       unsigned short* __restrict__ Wgb, unsigned short* __restrict__ Wvb) {
    int i = blockIdx.x * 256 + threadIdx.x;
    if (i < 65536) { Wsb[i] = f2b(Wsrc[i]); Wtb[i] = f2b(Wtgt[i]); Wpb[i] = f2b(Wp[i]); }
    if (i < 8192)  { Wgb[i] = f2b(Wg[i]);  Wvb[i] = f2b(Wv[i]); }
}

// ---------- counting sort by target ----------
__global__ void hist_k(const int* __restrict__ eidx, int* __restrict__ cnt, int E) {
    int i = blockIdx.x * 256 + threadIdx.x;
    if (i < E) atomicAdd(&cnt[eidx[E + i]], 1);
}

__global__ void scan_k(const int* __restrict__ cnt, int* __restrict__ cur, int N) {
    __shared__ int part[1024];
    int t = threadIdx.x;
    int C = (N + 1023) / 1024;
    int s = 0;
    for (int i = 0; i < C; i++) { int idx = t * C + i; if (idx < N) s += cnt[idx]; }
    part[t] = s;
    __syncthreads();
    for (int d = 1; d < 1024; d <<= 1) {
        int v = (t >= d) ? part[t - d] : 0;
        __syncthreads();
        part[t] += v;
        __syncthreads();
    }
    int base = (t == 0) ? 0 : part[t - 1];
    for (int i = 0; i < C; i++) {
        int idx = t * C + i;
        if (idx < N) { cur[idx] = base; base += cnt[idx]; }
    }
}

__global__ void scat_k(const int* __restrict__ eidx, int* __restrict__ cur,
                       int* __restrict__ perm, int E) {
    int i = blockIdx.x * 256 + threadIdx.x;
    if (i < E) { int p = atomicAdd(&cur[eidx[E + i]], 1); perm[p] = i; }
}

// ---------- node projections via MFMA, one pass per blockIdx.y ----------
__global__ __launch_bounds__(256, 2)
void proj_k(const float* __restrict__ x, const unsigned short* __restrict__ Wsb,
            const unsigned short* __restrict__ Wtb, float* __restrict__ xs,
            float* __restrict__ xt, int N) {
    __shared__ unsigned short ab[32 * 264];
    int t = threadIdx.x;
    int n0 = blockIdx.x * 32;
#pragma unroll
    for (int ch = 0; ch < 8; ch++) {
        int flat = ch * 1024 + t * 4;
        int row = flat >> 8, col = flat & 255;
        int n = n0 + row;
        float4 v = (n < N) ? *(const float4*)&x[(size_t)n * WID + col]
                           : make_float4(0.f, 0.f, 0.f, 0.f);
        unsigned int p0 = (unsigned int)f2b(v.x) | ((unsigned int)f2b(v.y) << 16);
        unsigned int p1 = (unsigned int)f2b(v.z) | ((unsigned int)f2b(v.w) << 16);
        *(uint2*)&ab[row * 264 + col] = make_uint2(p0, p1);
    }
    __syncthreads();
    const unsigned short* Wb = blockIdx.y ? Wtb : Wsb;
    float* outp = blockIdx.y ? xt : xs;
    int w = t >> 6, lane = t & 63, m = lane & 15, kg = lane >> 4;
    v4f acc[2][4];
#pragma unroll
    for (int mt = 0; mt < 2; mt++)
#pragma unroll
        for (int nt = 0; nt < 4; nt++) acc[mt][nt] = (v4f){0.f, 0.f, 0.f, 0.f};
#pragma unroll
    for (int kt = 0; kt < 8; kt++) {
        int k0 = kt * 32 + kg * 8;
        v8bf a0 = *(const v8bf*)&ab[m * 264 + k0];
        v8bf a1 = *(const v8bf*)&ab[(16 + m) * 264 + k0];
#pragma unroll
        for (int nt = 0; nt < 4; nt++) {
            int j = w * 64 + nt * 16 + m;
            v8bf b = *(const v8bf*)&Wb[j * 256 + k0];
            acc[0][nt] = __builtin_amdgcn_mfma_f32_16x16x32_bf16(a0, b, acc[0][nt], 0, 0, 0);
            acc[1][nt] = __builtin_amdgcn_mfma_f32_16x16x32_bf16(a1, b, acc[1][nt], 0, 0, 0);
        }
    }
#pragma unroll
    for (int mt = 0; mt < 2; mt++)
#pragma unroll
        for (int r = 0; r < 4; r++) {
            int n = n0 + mt * 16 + kg * 4 + r;
            if (n < N)
#pragma unroll
                for (int nt = 0; nt < 4; nt++)
                    outp[(size_t)n * WID + w * 64 + nt * 16 + m] = acc[mt][nt][r];
        }
}

// ---------- fused edge pipeline on target-sorted edges, bf16 LDS ----------
__global__ __launch_bounds__(256, 4)
void edge_k(const float* __restrict__ xs, const float* __restrict__ xt,
            const int* __restrict__ eidx, const int* __restrict__ eattr,
            const int* __restrict__ perm, const float* __restrict__ emb,
            const unsigned short* __restrict__ Wgb, const unsigned short* __restrict__ Wvb,
            float* __restrict__ aggact, int E) {
    __shared__ unsigned short xxb[32 * 264];   // raw x -> xn -> act (all bf16)
    __shared__ unsigned short ginb[32 * 264];  // gate input (bf16)
    __shared__ float mu_s[256], rs_s[256];
    __shared__ int perm_s[32], src_s[32], tgt_s[32], attr_s[96];

    int t = threadIdx.x;
    int e0 = blockIdx.x * 32;
    int ne = min(32, E - e0);

    if (t < 32) {
        int p = (t < ne) ? perm[e0 + t] : -1;
        perm_s[t] = p;
        src_s[t] = (p >= 0) ? eidx[p] : 0;
        tgt_s[t] = (p >= 0) ? eidx[E + p] : 0;
    }
    __syncthreads();
    if (t < 96) {
        int e = t / 3, c = t - e * 3;
        int p = perm_s[e];
        attr_s[t] = (p >= 0) ? eattr[(size_t)p * 3 + c] : 0;
    }

    // P1: burst gather xs[src]+xt[tgt]; fp32 stats in registers; bf16 store.
    // thread -> (edge e=t>>3, chunk c=t&7); chunk i covers head i (cols 4c+32i..+3)
    {
        int e = t >> 3, c = t & 7;
        int s = src_s[e], g = tgt_s[e];
        const float4* ps = (const float4*)&xs[(size_t)s * WID];
        const float4* pt = (const float4*)&xt[(size_t)g * WID];
        bool live = (e < ne);
        float4 a[8], b[8];
#pragma unroll
        for (int i = 0; i < 8; i++) { a[i] = ps[c + i * 8]; b[i] = pt[c + i * 8]; }
        float sum[8], sq[8];
#pragma unroll
        for (int i = 0; i < 8; i++) {
            float4 v;
            v.x = live ? a[i].x + b[i].x : 0.f;
            v.y = live ? a[i].y + b[i].y : 0.f;
            v.z = live ? a[i].z + b[i].z : 0.f;
            v.w = live ? a[i].w + b[i].w : 0.f;
            sum[i] = v.x + v.y + v.z + v.w;
            sq[i] = v.x * v.x + v.y * v.y + v.z * v.z + v.w * v.w;
            unsigned int p0 = (unsigned int)f2b(v.x) | ((unsigned int)f2b(v.y) << 16);
            unsigned int p1 = (unsigned int)f2b(v.z) | ((unsigned int)f2b(v.w) << 16);
            *(uint2*)&xxb[e * 264 + (c + i * 8) * 4] = make_uint2(p0, p1);
        }
        // butterfly over the 8 lanes of edge e
#pragma unroll
        for (int mask = 1; mask <= 4; mask <<= 1)
#pragma unroll
            for (int i = 0; i < 8; i++) {
                sum[i] += __shfl_xor(sum[i], mask);
                sq[i]  += __shfl_xor(sq[i], mask);
            }
        float fs = sum[0], fq = sq[0];
#pragma unroll
        for (int i = 1; i < 8; i++) if (c == i) { fs = sum[i]; fq = sq[i]; }
        float mu = fs * (1.f / 32.f);
        float var = fq * (1.f / 32.f) - mu * mu;
        mu_s[e * 8 + c] = mu;
        rs_s[e * 8 + c] = rsqrtf(var + EPS_GN);
    }
    __syncthreads();

    // P4: normalize (in place) + embedding-bag gate input. column t.
    {
        int h = t >> 5;
        for (int e = 0; e < 32; e++) {
            float mu = mu_s[e * 8 + h], rs = rs_s[e * 8 + h];
            float xn = (b2f(xxb[e * 264 + t]) - mu) * rs;
            float bsum = 0.f; int cnt = 0;
#pragma unroll
            for (int c = 0; c < 3; c++) {
                int idx = __builtin_amdgcn_readfirstlane(attr_s[e * 3 + c]);
                if (idx != 0) { bsum += emb[idx * WID + t]; cnt++; }
            }
            float gin = xn + ((cnt > 0) ? bsum * (1.f / (float)cnt) : 0.f);
            xxb[e * 264 + t] = f2b(xn);
            ginb[e * 264 + t] = f2b(gin);
        }
    }
    __syncthreads();

    // P5: frag loads -> barrier -> gate/val MFMA -> act (bf16) into xxb
    {
        int w = t >> 6, lane = t & 63;
        int m = lane & 15, kg = lane >> 4;
        v8bf av[2][2], ag[2][2], bg[2][2], bv[2][2];
#pragma unroll
        for (int hh = 0; hh < 2; hh++) {
            int h = w * 2 + hh;
            av[hh][0] = *(const v8bf*)&xxb[m * 264 + h * 32 + kg * 8];
            av[hh][1] = *(const v8bf*)&xxb[(16 + m) * 264 + h * 32 + kg * 8];
            ag[hh][0] = *(const v8bf*)&ginb[m * 264 + h * 32 + kg * 8];
            ag[hh][1] = *(const v8bf*)&ginb[(16 + m) * 264 + h * 32 + kg * 8];
            bg[hh][0] = *(const v8bf*)&Wgb[h * 1024 + m * 32 + kg * 8];
            bg[hh][1] = *(const v8bf*)&Wgb[h * 1024 + (16 + m) * 32 + kg * 8];
            bv[hh][0] = *(const v8bf*)&Wvb[h * 1024 + m * 32 + kg * 8];
            bv[hh][1] = *(const v8bf*)&Wvb[h * 1024 + (16 + m) * 32 + kg * 8];
        }
        __syncthreads();  // all xn frag reads done before act overwrites xxb
#pragma unroll
        for (int hh = 0; hh < 2; hh++) {
            int h = w * 2 + hh;
            v4f z = {0.f, 0.f, 0.f, 0.f};
            v4f g00 = __builtin_amdgcn_mfma_f32_16x16x32_bf16(ag[hh][0], bg[hh][0], z, 0, 0, 0);
            v4f g01 = __builtin_amdgcn_mfma_f32_16x16x32_bf16(ag[hh][0], bg[hh][1], z, 0, 0, 0);
            v4f g10 = __builtin_amdgcn_mfma_f32_16x16x32_bf16(ag[hh][1], bg[hh][0], z, 0, 0, 0);
            v4f g11 = __builtin_amdgcn_mfma_f32_16x16x32_bf16(ag[hh][1], bg[hh][1], z, 0, 0, 0);
            v4f v00 = __builtin_amdgcn_mfma_f32_16x16x32_bf16(av[hh][0], bv[hh][0], z, 0, 0, 0);
            v4f v01 = __builtin_amdgcn_mfma_f32_16x16x32_bf16(av[hh][0], bv[hh][1], z, 0, 0, 0);
            v4f v10 = __builtin_amdgcn_mfma_f32_16x16x32_bf16(av[hh][1], bv[hh][0], z, 0, 0, 0);
            v4f v11 = __builtin_amdgcn_mfma_f32_16x16x32_bf16(av[hh][1], bv[hh][1], z, 0, 0, 0);
            // C layout: row e = tile*16 + kg*4 + r, col = h*32 + (ntile*16 + m)
#pragma unroll
            for (int r = 0; r < 4; r++) {
                int eA = kg * 4 + r, eB = eA + 16;
                xxb[eA * 264 + h * 32 + m]      = f2b(fmaxf(g00[r], 0.f) * v00[r]);
                xxb[eA * 264 + h * 32 + 16 + m] = f2b(fmaxf(g01[r], 0.f) * v01[r]);
                xxb[eB * 264 + h * 32 + m]      = f2b(fmaxf(g10[r], 0.f) * v10[r]);
                xxb[eB * 264 + h * 32 + 16 + m] = f2b(fmaxf(g11[r], 0.f) * v11[r]);
            }
        }
    }
    __syncthreads();

    // P6: segmented column reduce over sorted targets
    {
        float sum = 0.f;
        int prev = __builtin_amdgcn_readfirstlane(tgt_s[0]);
        for (int e = 0; e < ne; e++) {
            int tg = __builtin_amdgcn_readfirstlane(tgt_s[e]);
            if (tg != prev) {
                atomicAdd(&aggact[(size_t)prev * WID + t], sum);
                sum = 0.f;
                prev = tg;
            }
            sum += b2f(xxb[e * 264 + t]);
        }
        atomicAdd(&aggact[(size_t)prev * WID + t], sum);
    }
}

// ---------- post: out = deg^p ⊙ (aggact @ Wp^T) ----------
__global__ __launch_bounds__(256, 2)
void post_k(const float* __restrict__ aggact, const unsigned short* __restrict__ Wpb,
            const float* __restrict__ deg, const float* __restrict__ dp,
            float* __restrict__ out, int N) {
    __shared__ unsigned short ab[32 * 264];
    __shared__ float degl[32];
    int t = threadIdx.x;
    int n0 = blockIdx.x * 32;
#pragma unroll
    for (int ch = 0; ch < 8; ch++) {
        int flat = ch * 1024 + t * 4;
        int row = flat >> 8, col = flat & 255;
        int n = n0 + row;
        float4 v = (n < N) ? *(const float4*)&aggact[(size_t)n * WID + col]
                           : make_float4(0.f, 0.f, 0.f, 0.f);
        unsigned int p0 = (unsigned int)f2b(v.x) | ((unsigned int)f2b(v.y) << 16);
        unsigned int p1 = (unsigned int)f2b(v.z) | ((unsigned int)f2b(v.w) << 16);
        *(uint2*)&ab[row * 264 + col] = make_uint2(p0, p1);
    }
    if (t < 32) {
        int n = n0 + t;
        degl[t] = (n < N) ? log2f(deg[n]) : 0.f;
    }
    __syncthreads();
    int w = t >> 6, lane = t & 63, m = lane & 15, kg = lane >> 4;
    v4f acc[2][4];
#pragma unroll
    for (int mt = 0; mt < 2; mt++)
#pragma unroll
        for (int nt = 0; nt < 4; nt++) acc[mt][nt] = (v4f){0.f, 0.f, 0.f, 0.f};
#pragma unroll
    for (int kt = 0; kt < 8; kt++) {
        int k0 = kt * 32 + kg * 8;
        v8bf a0 = *(const v8bf*)&ab[m * 264 + k0];
        v8bf a1 = *(const v8bf*)&ab[(16 + m) * 264 + k0];
#pragma unroll
        for (int nt = 0; nt < 4; nt++) {
            int j = w * 64 + nt * 16 + m;
            v8bf b = *(const v8bf*)&Wpb[j * 256 + k0];
            acc[0][nt] = __builtin_amdgcn_mfma_f32_16x16x32_bf16(a0, b, acc[0][nt], 0, 0, 0);
            acc[1][nt] = __builtin_amdgcn_mfma_f32_16x16x32_bf16(a1, b, acc[1][nt], 0, 0, 0);
        }
    }
    float dpv[4];
#pragma unroll
    for (int nt = 0; nt < 4; nt++) dpv[nt] = dp[w * 64 + nt * 16 + m];
#pragma unroll
    for (int mt = 0; mt < 2; mt++)
#pragma unroll
        for (int r = 0; r < 4; r++) {
            int row = mt * 16 + kg * 4 + r;
            int n = n0 + row;
            if (n < N) {
                float ld = degl[row];
#pragma unroll
                for (int nt = 0; nt < 4; nt++)
                    out[(size_t)n * WID + w * 64 + nt * 16 + m] =
                        exp2f(dpv[nt] * ld) * acc[mt][nt][r];
            }
        }
}

extern "C" void kernel_launch(void* const* d_in, const int* in_sizes, int n_in,
                              void* d_out, int out_size, void* d_ws, size_t ws_size,
                              hipStream_t stream) {
    const float* x    = (const float*)d_in[0];
    const float* deg  = (const float*)d_in[1];
    const int*   eidx = (const int*)d_in[2];
    const int*   eatt = (const int*)d_in[3];
    const float* Wsrc = (const float*)d_in[4];
    const float* Wtgt = (const float*)d_in[5];
    const float* emb  = (const float*)d_in[6];
    const float* Wg   = (const float*)d_in[7];
    const float* Wv   = (const float*)d_in[8];
    const float* Wp   = (const float*)d_in[9];
    const float* dp   = (const float*)d_in[10];
    int N = in_sizes[0] / WID;
    int E = in_sizes[2] / 2;

    float* ws     = (float*)d_ws;
    float* xs     = ws;                         // N*W
    float* xt     = xs + (size_t)N * WID;       // N*W
    float* aggact = xt + (size_t)N * WID;       // N*W
    int*   cnt    = (int*)(aggact + (size_t)N * WID);  // N (zeroed with aggact)
    int*   cur    = cnt + N;                    // N
    int*   perm   = cur + N;                    // E
    unsigned short* Wsb = (unsigned short*)(perm + E);
    unsigned short* Wtb = Wsb + 65536;
    unsigned short* Wpb = Wtb + 65536;
    unsigned short* Wgb = Wpb + 65536;
    unsigned short* Wvb = Wgb + 8192;

    hipMemsetAsync(aggact, 0, ((size_t)N * WID + N) * sizeof(float), stream);
    cast_k<<<256, 256, 0, stream>>>(Wsrc, Wtgt, Wp, Wg, Wv, Wsb, Wtb, Wpb, Wgb, Wvb);
    hist_k<<<(E + 255) / 256, 256, 0, stream>>>(eidx, cnt, E);
    scan_k<<<1, 1024, 0, stream>>>(cnt, cur, N);
    scat_k<<<(E + 255) / 256, 256, 0, stream>>>(eidx, cur, perm, E);
    proj_k<<<dim3((N + 31) / 32, 2), 256, 0, stream>>>(x, Wsb, Wtb, xs, xt, N);
    edge_k<<<(E + 31) / 32, 256, 0, stream>>>(xs, xt, eidx, eatt, perm, emb, Wgb, Wvb, aggact, E);
    post_k<<<(N + 31) / 32, 256, 0, stream>>>(aggact, Wpb, deg, dp, (float*)d_out, N);
}

// Round 6
// 244.029 us; speedup vs baseline: 1.9628x; 1.7495x over previous
//
#include <hip/hip_runtime.h>

#define WID 256
#define EPS_GN 1e-5f

typedef __bf16 v8bf __attribute__((ext_vector_type(8)));
typedef float  v4f  __attribute__((ext_vector_type(4)));

__device__ inline unsigned short f2b(float f) {
    unsigned int u = __builtin_bit_cast(unsigned int, f);
    unsigned int r = (u + 0x7fffu + ((u >> 16) & 1u)) >> 16;
    return (unsigned short)r;
}
__device__ inline float b2f(unsigned short s) {
    unsigned int u = (unsigned int)s << 16;
    return __builtin_bit_cast(float, u);
}
__device__ inline float lo16(unsigned int u) { return __builtin_bit_cast(float, u << 16); }
__device__ inline float hi16(unsigned int u) { return __builtin_bit_cast(float, u & 0xffff0000u); }

// ---------- prep: cast weights to bf16 + embWg^T + target histogram ----------
__global__ void prep_k(const float* __restrict__ Wsrc, const float* __restrict__ Wtgt,
                       const float* __restrict__ Wp, const float* __restrict__ Wg,
                       const float* __restrict__ Wv, const float* __restrict__ emb,
                       const int* __restrict__ eidx,
                       unsigned short* __restrict__ Wsb, unsigned short* __restrict__ Wtb,
                       unsigned short* __restrict__ Wpb, unsigned short* __restrict__ Wgb,
                       unsigned short* __restrict__ Wvb, unsigned short* __restrict__ embWgT,
                       int* __restrict__ cnt, int E, int BOND) {
    int b = blockIdx.x, t = threadIdx.x;
    if (b < 256) {
        int i = b * 256 + t;
        Wsb[i] = f2b(Wsrc[i]); Wtb[i] = f2b(Wtgt[i]); Wpb[i] = f2b(Wp[i]);
        if (i < 8192) { Wgb[i] = f2b(Wg[i]); Wvb[i] = f2b(Wv[i]); }
    } else {
        // embWgT[j][k] = sum_d emb[k][h*32+d] * Wg[h][f][d], j = h*32+f, k padded to 64
        int k = b - 256;  // 0..63
        float s = 0.f;
        if (k < BOND) {
            int h = t >> 5, f = t & 31;
            const float* er = emb + (size_t)k * WID + h * 32;
            const float* wr = Wg + h * 1024 + f * 32;
#pragma unroll
            for (int d = 0; d < 32; d++) s += er[d] * wr[d];
        }
        embWgT[t * 64 + k] = f2b(s);
    }
    // histogram (grid-stride over all 320 blocks)
    for (int i = b * 256 + t; i < E; i += 320 * 256)
        atomicAdd(&cnt[eidx[E + i]], 1);
}

// ---------- exclusive scan ----------
__global__ void scan_k(const int* __restrict__ cnt, int* __restrict__ cur, int N) {
    __shared__ int part[1024];
    int t = threadIdx.x;
    int C = (N + 1023) / 1024;
    int s = 0;
    for (int i = 0; i < C; i++) { int idx = t * C + i; if (idx < N) s += cnt[idx]; }
    part[t] = s;
    __syncthreads();
    for (int d = 1; d < 1024; d <<= 1) {
        int v = (t >= d) ? part[t - d] : 0;
        __syncthreads();
        part[t] += v;
        __syncthreads();
    }
    int base = (t == 0) ? 0 : part[t - 1];
    for (int i = 0; i < C; i++) {
        int idx = t * C + i;
        if (idx < N) { cur[idx] = base; base += cnt[idx]; }
    }
}

__global__ void scat_k(const int* __restrict__ eidx, int* __restrict__ cur,
                       int* __restrict__ perm, int E) {
    int i = blockIdx.x * 256 + threadIdx.x;
    if (i < E) { int p = atomicAdd(&cur[eidx[E + i]], 1); perm[p] = i; }
}

// ---------- node projections via MFMA -> bf16 outputs ----------
__global__ __launch_bounds__(256, 2)
void proj_k(const float* __restrict__ x, const unsigned short* __restrict__ Wsb,
            const unsigned short* __restrict__ Wtb, unsigned short* __restrict__ xsb,
            unsigned short* __restrict__ xtb, int N) {
    __shared__ unsigned short ab[32 * 264];
    int t = threadIdx.x;
    int n0 = blockIdx.x * 32;
#pragma unroll
    for (int ch = 0; ch < 8; ch++) {
        int flat = ch * 1024 + t * 4;
        int row = flat >> 8, col = flat & 255;
        int n = n0 + row;
        float4 v = (n < N) ? *(const float4*)&x[(size_t)n * WID + col]
                           : make_float4(0.f, 0.f, 0.f, 0.f);
        unsigned int p0 = (unsigned int)f2b(v.x) | ((unsigned int)f2b(v.y) << 16);
        unsigned int p1 = (unsigned int)f2b(v.z) | ((unsigned int)f2b(v.w) << 16);
        *(uint2*)&ab[row * 264 + col] = make_uint2(p0, p1);
    }
    __syncthreads();
    const unsigned short* Wb = blockIdx.y ? Wtb : Wsb;
    unsigned short* outp = blockIdx.y ? xtb : xsb;
    int w = t >> 6, lane = t & 63, m = lane & 15, kg = lane >> 4;
    v4f acc[2][4];
#pragma unroll
    for (int mt = 0; mt < 2; mt++)
#pragma unroll
        for (int nt = 0; nt < 4; nt++) acc[mt][nt] = (v4f){0.f, 0.f, 0.f, 0.f};
#pragma unroll
    for (int kt = 0; kt < 8; kt++) {
        int k0 = kt * 32 + kg * 8;
        v8bf a0 = *(const v8bf*)&ab[m * 264 + k0];
        v8bf a1 = *(const v8bf*)&ab[(16 + m) * 264 + k0];
#pragma unroll
        for (int nt = 0; nt < 4; nt++) {
            int j = w * 64 + nt * 16 + m;
            v8bf b = *(const v8bf*)&Wb[j * 256 + k0];
            acc[0][nt] = __builtin_amdgcn_mfma_f32_16x16x32_bf16(a0, b, acc[0][nt], 0, 0, 0);
            acc[1][nt] = __builtin_amdgcn_mfma_f32_16x16x32_bf16(a1, b, acc[1][nt], 0, 0, 0);
        }
    }
#pragma unroll
    for (int mt = 0; mt < 2; mt++)
#pragma unroll
        for (int r = 0; r < 4; r++) {
            int n = n0 + mt * 16 + kg * 4 + r;
            if (n < N)
#pragma unroll
                for (int nt = 0; nt < 4; nt++)
                    outp[(size_t)n * WID + w * 64 + nt * 16 + m] = f2b(acc[mt][nt][r]);
        }
}

// ---------- fused edge pipeline: gather+GN -> gate/val(+bag via M@embWg) MFMA -> seg-reduce ----------
__global__ __launch_bounds__(256, 6)
void edge_k(const unsigned short* __restrict__ xsb, const unsigned short* __restrict__ xtb,
            const int* __restrict__ eidx, const int* __restrict__ eattr,
            const int* __restrict__ perm, const unsigned short* __restrict__ Wgb,
            const unsigned short* __restrict__ Wvb, const unsigned short* __restrict__ embWgT,
            float* __restrict__ aggact, int E) {
    __shared__ unsigned short xxb[32 * 264];  // xn (bf16) -> act (bf16)
    __shared__ unsigned short Mld[32 * 72];   // bag mixing matrix, K padded to 64
    __shared__ int src_s[32], tgt_s[32];

    int t = threadIdx.x;
    int e0 = blockIdx.x * 32;
    int ne = min(32, E - e0);

    // Phase A (t<32): indices + build M row for edge t
    if (t < 32) {
        int p = (t < ne) ? perm[e0 + t] : -1;
        src_s[t] = (p >= 0) ? eidx[p] : 0;
        tgt_s[t] = (p >= 0) ? eidx[E + p] : 0;
        int a0 = 0, a1 = 0, a2 = 0;
        if (p >= 0) {
            const int* ap = eattr + (size_t)p * 3;
            a0 = ap[0]; a1 = ap[1]; a2 = ap[2];
        }
        unsigned int* Mr = (unsigned int*)&Mld[t * 72];
#pragma unroll
        for (int q = 0; q < 32; q++) Mr[q] = 0;
        int c = (a0 != 0) + (a1 != 0) + (a2 != 0);
        float inv = (p >= 0 && c > 0) ? 1.f / (float)c : 0.f;
        float wa = inv * (float)(1 + (a1 == a0) + (a2 == a0));
        float wb = inv * (float)(1 + (a2 == a1));
        Mld[t * 72 + a0] = f2b(wa);
        if (a1 != a0) Mld[t * 72 + a1] = f2b(wb);
        if (a2 != a0 && a2 != a1) Mld[t * 72 + a2] = f2b(inv);
    }
    __syncthreads();

    // P1: gather bf16 xs[src]+xt[tgt], GN stats via 4-lane butterfly, normalize, store bf16.
    // thread (e=t>>3, c=t&7); chunk i (uint4 #(c+8i)) = 8 cols of head 2i + c/4
    {
        int e = t >> 3, c = t & 7;
        int s = src_s[e], g = tgt_s[e];
        bool live = (e < ne);
        const uint4* ps = (const uint4*)(xsb + (size_t)s * WID);
        const uint4* pt = (const uint4*)(xtb + (size_t)g * WID);
        uint4 us[4], ut[4];
#pragma unroll
        for (int i = 0; i < 4; i++) { us[i] = ps[c + 8 * i]; ut[i] = pt[c + 8 * i]; }
        float v[4][8], sum[4], sq[4];
#pragma unroll
        for (int i = 0; i < 4; i++) {
            const unsigned int* au = (const unsigned int*)&us[i];
            const unsigned int* bu = (const unsigned int*)&ut[i];
            sum[i] = 0.f; sq[i] = 0.f;
#pragma unroll
            for (int q = 0; q < 4; q++) {
                float x0 = lo16(au[q]) + lo16(bu[q]);
                float x1 = hi16(au[q]) + hi16(bu[q]);
                if (!live) { x0 = 0.f; x1 = 0.f; }
                v[i][2 * q] = x0; v[i][2 * q + 1] = x1;
                sum[i] += x0 + x1;
                sq[i] += x0 * x0 + x1 * x1;
            }
        }
#pragma unroll
        for (int mask = 1; mask <= 2; mask <<= 1)
#pragma unroll
            for (int i = 0; i < 4; i++) {
                sum[i] += __shfl_xor(sum[i], mask);
                sq[i]  += __shfl_xor(sq[i], mask);
            }
#pragma unroll
        for (int i = 0; i < 4; i++) {
            float mu = sum[i] * (1.f / 32.f);
            float var = sq[i] * (1.f / 32.f) - mu * mu;
            float rs = rsqrtf(var + EPS_GN);
            unsigned int pk[4];
#pragma unroll
            for (int q = 0; q < 4; q++) {
                unsigned int l = f2b((v[i][2 * q] - mu) * rs);
                unsigned int h = f2b((v[i][2 * q + 1] - mu) * rs);
                pk[q] = l | (h << 16);
            }
            *(uint4*)&xxb[e * 264 + (c + 8 * i) * 8] = make_uint4(pk[0], pk[1], pk[2], pk[3]);
        }
    }
    __syncthreads();

    // P5: gate = relu(xn@Wg + M@embWg), val = xn@Wv, act -> xxb (each wave owns its 64 cols)
    {
        int w = t >> 6, lane = t & 63, m = lane & 15, kg = lane >> 4;
        v8bf axn[2][2], aM[2][2];
#pragma unroll
        for (int mt = 0; mt < 2; mt++) {
            int row = mt * 16 + m;
            axn[0][mt] = *(const v8bf*)&xxb[row * 264 + (w * 2 + 0) * 32 + kg * 8];
            axn[1][mt] = *(const v8bf*)&xxb[row * 264 + (w * 2 + 1) * 32 + kg * 8];
            aM[mt][0] = *(const v8bf*)&Mld[row * 72 + kg * 8];
            aM[mt][1] = *(const v8bf*)&Mld[row * 72 + 32 + kg * 8];
        }
        v4f z = {0.f, 0.f, 0.f, 0.f};
#pragma unroll
        for (int hh = 0; hh < 2; hh++) {
            int h = w * 2 + hh;
#pragma unroll
            for (int nt = 0; nt < 2; nt++) {
                int fj = nt * 16 + m;
                int j = h * 32 + fj;
                v8bf bWg = *(const v8bf*)&Wgb[h * 1024 + fj * 32 + kg * 8];
                v8bf bWv = *(const v8bf*)&Wvb[h * 1024 + fj * 32 + kg * 8];
                v8bf bE0 = *(const v8bf*)&embWgT[j * 64 + kg * 8];
                v8bf bE1 = *(const v8bf*)&embWgT[j * 64 + 32 + kg * 8];
#pragma unroll
                for (int mt = 0; mt < 2; mt++) {
                    v4f cg = __builtin_amdgcn_mfma_f32_16x16x32_bf16(axn[hh][mt], bWg, z, 0, 0, 0);
                    cg = __builtin_amdgcn_mfma_f32_16x16x32_bf16(aM[mt][0], bE0, cg, 0, 0, 0);
                    cg = __builtin_amdgcn_mfma_f32_16x16x32_bf16(aM[mt][1], bE1, cg, 0, 0, 0);
                    v4f cv = __builtin_amdgcn_mfma_f32_16x16x32_bf16(axn[hh][mt], bWv, z, 0, 0, 0);
#pragma unroll
                    for (int r = 0; r < 4; r++) {
                        int e = mt * 16 + kg * 4 + r;
                        xxb[e * 264 + j] = f2b(fmaxf(cg[r], 0.f) * cv[r]);
                    }
                }
            }
        }
    }
    __syncthreads();

    // P6: segmented column reduce over sorted targets
    {
        float sum = 0.f;
        int prev = __builtin_amdgcn_readfirstlane(tgt_s[0]);
        for (int e = 0; e < ne; e++) {
            int tg = __builtin_amdgcn_readfirstlane(tgt_s[e]);
            if (tg != prev) {
                atomicAdd(&aggact[(size_t)prev * WID + t], sum);
                sum = 0.f;
                prev = tg;
            }
            sum += b2f(xxb[e * 264 + t]);
        }
        atomicAdd(&aggact[(size_t)prev * WID + t], sum);
    }
}

// ---------- post: out = deg^p ⊙ (aggact @ Wp^T) ----------
__global__ __launch_bounds__(256, 2)
void post_k(const float* __restrict__ aggact, const unsigned short* __restrict__ Wpb,
            const float* __restrict__ deg, const float* __restrict__ dp,
            float* __restrict__ out, int N) {
    __shared__ unsigned short ab[32 * 264];
    __shared__ float degl[32];
    int t = threadIdx.x;
    int n0 = blockIdx.x * 32;
#pragma unroll
    for (int ch = 0; ch < 8; ch++) {
        int flat = ch * 1024 + t * 4;
        int row = flat >> 8, col = flat & 255;
        int n = n0 + row;
        float4 v = (n < N) ? *(const float4*)&aggact[(size_t)n * WID + col]
                           : make_float4(0.f, 0.f, 0.f, 0.f);
        unsigned int p0 = (unsigned int)f2b(v.x) | ((unsigned int)f2b(v.y) << 16);
        unsigned int p1 = (unsigned int)f2b(v.z) | ((unsigned int)f2b(v.w) << 16);
        *(uint2*)&ab[row * 264 + col] = make_uint2(p0, p1);
    }
    if (t < 32) {
        int n = n0 + t;
        degl[t] = (n < N) ? log2f(deg[n]) : 0.f;
    }
    __syncthreads();
    int w = t >> 6, lane = t & 63, m = lane & 15, kg = lane >> 4;
    v4f acc[2][4];
#pragma unroll
    for (int mt = 0; mt < 2; mt++)
#pragma unroll
        for (int nt = 0; nt < 4; nt++) acc[mt][nt] = (v4f){0.f, 0.f, 0.f, 0.f};
#pragma unroll
    for (int kt = 0; kt < 8; kt++) {
        int k0 = kt * 32 + kg * 8;
        v8bf a0 = *(const v8bf*)&ab[m * 264 + k0];
        v8bf a1 = *(const v8bf*)&ab[(16 + m) * 264 + k0];
#pragma unroll
        for (int nt = 0; nt < 4; nt++) {
            int j = w * 64 + nt * 16 + m;
            v8bf b = *(const v8bf*)&Wpb[j * 256 + k0];
            acc[0][nt] = __builtin_amdgcn_mfma_f32_16x16x32_bf16(a0, b, acc[0][nt], 0, 0, 0);
            acc[1][nt] = __builtin_amdgcn_mfma_f32_16x16x32_bf16(a1, b, acc[1][nt], 0, 0, 0);
        }
    }
    float dpv[4];
#pragma unroll
    for (int nt = 0; nt < 4; nt++) dpv[nt] = dp[w * 64 + nt * 16 + m];
#pragma unroll
    for (int mt = 0; mt < 2; mt++)
#pragma unroll
        for (int r = 0; r < 4; r++) {
            int row = mt * 16 + kg * 4 + r;
            int n = n0 + row;
            if (n < N) {
                float ld = degl[row];
#pragma unroll
                for (int nt = 0; nt < 4; nt++)
                    out[(size_t)n * WID + w * 64 + nt * 16 + m] =
                        exp2f(dpv[nt] * ld) * acc[mt][nt][r];
            }
        }
}

extern "C" void kernel_launch(void* const* d_in, const int* in_sizes, int n_in,
                              void* d_out, int out_size, void* d_ws, size_t ws_size,
                              hipStream_t stream) {
    const float* x    = (const float*)d_in[0];
    const float* deg  = (const float*)d_in[1];
    const int*   eidx = (const int*)d_in[2];
    const int*   eatt = (const int*)d_in[3];
    const float* Wsrc = (const float*)d_in[4];
    const float* Wtgt = (const float*)d_in[5];
    const float* emb  = (const float*)d_in[6];
    const float* Wg   = (const float*)d_in[7];
    const float* Wv   = (const float*)d_in[8];
    const float* Wp   = (const float*)d_in[9];
    const float* dp   = (const float*)d_in[10];
    int N = in_sizes[0] / WID;
    int E = in_sizes[2] / 2;
    int BOND = in_sizes[6] / WID;

    float* ws     = (float*)d_ws;
    float* aggact = ws;                                   // N*W floats
    int*   cnt    = (int*)(aggact + (size_t)N * WID);     // N (zeroed with aggact)
    int*   cur    = cnt + N;                              // N
    int*   perm   = cur + N;                              // E
    unsigned short* xsb = (unsigned short*)(perm + E);    // N*W bf16
    unsigned short* xtb = xsb + (size_t)N * WID;          // N*W bf16
    unsigned short* Wsb = xtb + (size_t)N * WID;
    unsigned short* Wtb = Wsb + 65536;
    unsigned short* Wpb = Wtb + 65536;
    unsigned short* Wgb = Wpb + 65536;
    unsigned short* Wvb = Wgb + 8192;
    unsigned short* embWgT = Wvb + 8192;                  // 256*64 bf16

    hipMemsetAsync(aggact, 0, ((size_t)N * WID + N) * sizeof(float), stream);
    prep_k<<<320, 256, 0, stream>>>(Wsrc, Wtgt, Wp, Wg, Wv, emb, eidx,
                                    Wsb, Wtb, Wpb, Wgb, Wvb, embWgT, cnt, E, BOND);
    scan_k<<<1, 1024, 0, stream>>>(cnt, cur, N);
    scat_k<<<(E + 255) / 256, 256, 0, stream>>>(eidx, cur, perm, E);
    proj_k<<<dim3((N + 31) / 32, 2), 256, 0, stream>>>(x, Wsb, Wtb, xsb, xtb, N);
    edge_k<<<(E + 31) / 32, 256, 0, stream>>>(xsb, xtb, eidx, eatt, perm, Wgb, Wvb, embWgT, aggact, E);
    post_k<<<(N + 31) / 32, 256, 0, stream>>>(aggact, Wpb, deg, dp, (float*)d_out, N);
}